// Round 20
// baseline (873.083 us; speedup 1.0000x reference)
//
#include <hip/hip_runtime.h>

constexpr int N_NODES = 100000;
constexpr int N_EDGES = 1600000;
constexpr int NBK  = 391;
constexpr int NBLK = 640;
constexpr int CHUNK = 2500;
constexpr int LCNT = NBK * NBLK;
constexpr int SCAN_BLKS = (LCNT + 255) / 256;
constexpr size_t YST = (size_t)N_NODES * 9;   // u64 per 36-col split buffer

// ---------------- bf16 helpers (RNE) ----------------

__device__ __forceinline__ unsigned bf16pack(float a, float b) {
    unsigned ua = __float_as_uint(a), ub = __float_as_uint(b);
    ua += 0x7fffu + ((ua >> 16) & 1u);
    ub += 0x7fffu + ((ub >> 16) & 1u);
    return (ua >> 16) | (ub & 0xffff0000u);
}
__device__ __forceinline__ float bflo(unsigned p) { return __uint_as_float(p << 16); }
__device__ __forceinline__ float bfhi(unsigned p) { return __uint_as_float(p & 0xffff0000u); }

// packed edge: bits 0..16 = src; bits 17..31 = 15-bit weight (implicit negative)
__device__ __forceinline__ int esrc(unsigned v) { return (int)(v & 0x1FFFFu); }
__device__ __forceinline__ float ew(unsigned v) {
    return __uint_as_float(0x80000000u | ((v >> 17) << 16));
}

// Split bf16 36-col buffer: A-region [N][8 u64] (cols 0..31, 64B rows),
// B-region [N][1 u64] (cols 32..35) at u64 offset N*8. Lane c in 0..8.
__device__ __forceinline__ size_t sidx(int c, int row) {
    return (c < 8) ? ((size_t)row * 8 + c) : ((size_t)N_NODES * 8 + row);
}

// ---------------- preprocessing (proven, unchanged) ----------------

__global__ __launch_bounds__(256) void part_count_kernel(
    const int* __restrict__ ei, int* __restrict__ cntD, int* __restrict__ cntS) {
    __shared__ int hd[NBK], hs[NBK];
    int tid = threadIdx.x;
    for (int i = tid; i < NBK; i += 256) { hd[i] = 0; hs[i] = 0; }
    __syncthreads();
    int e0 = blockIdx.x * CHUNK;
    for (int e = e0 + tid; e < e0 + CHUNK; e += 256) {
        int s = ei[e], d = ei[N_EDGES + e];
        atomicAdd(&hs[s >> 8], 1);
        atomicAdd(&hd[d >> 8], 1);
    }
    __syncthreads();
    for (int i = tid; i < NBK; i += 256) {
        cntD[i * NBLK + blockIdx.x] = hd[i];
        cntS[i * NBLK + blockIdx.x] = hs[i];
    }
}

__global__ __launch_bounds__(256) void scanA_kernel(const int* __restrict__ in,
                                                    int* __restrict__ out,
                                                    int* __restrict__ bsum, int L) {
    __shared__ int sm[256];
    int i = blockIdx.x * 256 + threadIdx.x;
    int v = (i < L) ? in[i] : 0;
    sm[threadIdx.x] = v;
    __syncthreads();
    for (int off = 1; off < 256; off <<= 1) {
        int t = (threadIdx.x >= off) ? sm[threadIdx.x - off] : 0;
        __syncthreads();
        sm[threadIdx.x] += t;
        __syncthreads();
    }
    if (i < L) out[i] = sm[threadIdx.x] - v;
    if (threadIdx.x == 255) bsum[blockIdx.x] = sm[255];
}

__global__ __launch_bounds__(1024) void scanB_kernel(int* __restrict__ bsum, int nb) {
    __shared__ int sm[1024];
    int t = threadIdx.x;
    int v = (t < nb) ? bsum[t] : 0;
    sm[t] = v;
    __syncthreads();
    for (int off = 1; off < 1024; off <<= 1) {
        int u = (t >= off) ? sm[t - off] : 0;
        __syncthreads();
        sm[t] += u;
        __syncthreads();
    }
    if (t < nb) bsum[t] = sm[t] - v;
}

__global__ __launch_bounds__(256) void scanC_kernel(int* __restrict__ out,
                                                    const int* __restrict__ bsum, int L) {
    int i = blockIdx.x * 256 + threadIdx.x;
    if (i < L) out[i] += bsum[blockIdx.x];
}

__global__ __launch_bounds__(256) void part_scatter_kernel(
    const int* __restrict__ ei, const int* __restrict__ scanD,
    const int* __restrict__ scanS, int2* __restrict__ edgepart,
    int* __restrict__ srcpart) {
    __shared__ int curD[NBK], curS[NBK];
    int tid = threadIdx.x;
    for (int i = tid; i < NBK; i += 256) {
        curD[i] = scanD[i * NBLK + blockIdx.x];
        curS[i] = scanS[i * NBLK + blockIdx.x];
    }
    __syncthreads();
    int e0 = blockIdx.x * CHUNK;
    for (int e = e0 + tid; e < e0 + CHUNK; e += 256) {
        int s = ei[e], d = ei[N_EDGES + e];
        int pd = atomicAdd(&curD[d >> 8], 1);
        edgepart[pd] = make_int2(s, d);
        int ps = atomicAdd(&curS[s >> 8], 1);
        srcpart[ps] = s;
    }
}

__global__ __launch_bounds__(256) void deg_kernel(const int* __restrict__ srcpart,
                                                  const int* __restrict__ scanS,
                                                  float* __restrict__ dis) {
    __shared__ int cnt[256];
    int b = blockIdx.x, tid = threadIdx.x;
    cnt[tid] = 0;
    __syncthreads();
    int beg = scanS[b * NBLK];
    int end = (b + 1 < NBK) ? scanS[(b + 1) * NBLK] : N_EDGES;
    for (int j = beg + tid; j < end; j += 256)
        atomicAdd(&cnt[srcpart[j] & 255], 1);
    __syncthreads();
    int node = b * 256 + tid;
    if (node < N_NODES) dis[node] = cnt[tid] > 0 ? rsqrtf((float)cnt[tid]) : 0.f;
}

__global__ __launch_bounds__(256) void csr_kernel(const int2* __restrict__ edgepart,
                                                  const int* __restrict__ scanD,
                                                  const float* __restrict__ dis,
                                                  int* __restrict__ rp,
                                                  unsigned* __restrict__ csrc) {
    __shared__ int cnt[256];
    __shared__ int lofs[256];
    __shared__ float disl[256];
    int b = blockIdx.x, tid = threadIdx.x;
    int beg = scanD[b * NBLK];
    int end = (b + 1 < NBK) ? scanD[(b + 1) * NBLK] : N_EDGES;
    int node = b * 256 + tid;
    cnt[tid] = 0;
    disl[tid] = (node < N_NODES) ? dis[node] : 0.f;
    __syncthreads();
    for (int j = beg + tid; j < end; j += 256)
        atomicAdd(&cnt[edgepart[j].y & 255], 1);
    __syncthreads();
    int v = cnt[tid];
    lofs[tid] = v;
    __syncthreads();
    for (int off = 1; off < 256; off <<= 1) {
        int t = (tid >= off) ? lofs[tid - off] : 0;
        __syncthreads();
        lofs[tid] += t;
        __syncthreads();
    }
    int myexc = lofs[tid] - v;
    if (node < N_NODES) rp[node] = beg + myexc;
    if (b == NBK - 1 && tid == 0) rp[N_NODES] = N_EDGES;
    __syncthreads();
    lofs[tid] = myexc;
    cnt[tid] = 0;
    __syncthreads();
    for (int j = beg + tid; j < end; j += 256) {
        int2 e = edgepart[j];
        int dl = e.y & 255;
        int pos = beg + lofs[dl] + atomicAdd(&cnt[dl], 1);
        unsigned u = __float_as_uint(-(dis[e.x] * disl[dl]));
        u += 0x7fffu + ((u >> 16) & 1u);
        unsigned wb = (u >> 16) & 0x7FFFu;
        csrc[pos] = (unsigned)e.x | (wb << 17);
    }
}

// pack x [N,64] f32 -> bf16 row-major (16 u64 = 128B rows)
__global__ void pack_x_kernel(const float* __restrict__ x, uint2* __restrict__ xbf) {
    int i = blockIdx.x * blockDim.x + threadIdx.x;
    if (i >= N_NODES * 16) return;
    float4 v = ((const float4*)x)[i];
    xbf[i] = make_uint2(bf16pack(v.x, v.y), bf16pack(v.z, v.w));
}

// ---------------- batched projection, 4x4 reg tiles, kk-chunked grid ----------

template <int FI, int NK, int KPB, bool BN_A, bool EXTRA, bool BIAS_RELU, bool FUSE_STATS>
__global__ __launch_bounds__(256) void batchproj_kernel(
    const unsigned long long* __restrict__ Ab, const float* __restrict__ W,
    const float* __restrict__ Wx, const float* __restrict__ ss,
    const float* __restrict__ bias, unsigned long long* __restrict__ Y,
    float* __restrict__ partials, int pblks) {
    constexpr int RU2 = FI / 4;
    constexpr int NKT = NK + (EXTRA ? 1 : 0);
    __shared__ float Wl[FI * 36];
    __shared__ float Atile[112][FI + 1];
    __shared__ float ls[72];
    int tid = threadIdx.x;                       // 252 = 28 row-groups x 9 lanes
    int blk = blockIdx.x % pblks;
    int kk0 = (blockIdx.x / pblks) * KPB;
    int kk1 = min(kk0 + KPB, NKT);
    int r0 = blk * 112;
    for (int i = tid; i < 112 * RU2; i += 252) {
        int r = i / RU2, u = i % RU2;
        int row = r0 + r;
        long long av = 0;
        if (row < N_NODES) {
            size_t idx = (FI == 64) ? ((size_t)row * 16 + u) : sidx(u, row);
            av = (long long)Ab[idx];
        }
        unsigned lo = (unsigned)av, hi = (unsigned)(av >> 32);
        float f0 = bflo(lo), f1 = bfhi(lo), f2 = bflo(hi), f3 = bfhi(hi);
        if (BN_A) {
            int f = u * 4;
            f0 = fmaxf(fmaf(ss[f + 0], f0, ss[36 + f + 0]), 0.f);
            f1 = fmaxf(fmaf(ss[f + 1], f1, ss[36 + f + 1]), 0.f);
            f2 = fmaxf(fmaf(ss[f + 2], f2, ss[36 + f + 2]), 0.f);
            f3 = fmaxf(fmaf(ss[f + 3], f3, ss[36 + f + 3]), 0.f);
        }
        Atile[r][u * 4 + 0] = f0; Atile[r][u * 4 + 1] = f1;
        Atile[r][u * 4 + 2] = f2; Atile[r][u * 4 + 3] = f3;
    }
    if (FUSE_STATS && tid < 72) ls[tid] = 0.f;
    int g = tid / 9, c = tid % 9;
    int rr = 4 * g;
    for (int kk = kk0; kk < kk1; ++kk) {
        const float* Wk = (EXTRA && kk == NK) ? Wx : (W + (size_t)kk * FI * 36);
        __syncthreads();
        for (int i = tid; i < FI * 36; i += 252) Wl[i] = Wk[i];
        __syncthreads();
        float a00 = 0, a01 = 0, a02 = 0, a03 = 0;
        float a10 = 0, a11 = 0, a12 = 0, a13 = 0;
        float a20 = 0, a21 = 0, a22 = 0, a23 = 0;
        float a30 = 0, a31 = 0, a32 = 0, a33 = 0;
        const float4* Wl4 = (const float4*)Wl;
#pragma unroll 4
        for (int f = 0; f < FI; ++f) {
            float4 wv = Wl4[f * 9 + c];
            float v0 = Atile[rr + 0][f];
            float v1 = Atile[rr + 1][f];
            float v2 = Atile[rr + 2][f];
            float v3 = Atile[rr + 3][f];
            a00 = fmaf(v0, wv.x, a00); a01 = fmaf(v0, wv.y, a01);
            a02 = fmaf(v0, wv.z, a02); a03 = fmaf(v0, wv.w, a03);
            a10 = fmaf(v1, wv.x, a10); a11 = fmaf(v1, wv.y, a11);
            a12 = fmaf(v1, wv.z, a12); a13 = fmaf(v1, wv.w, a13);
            a20 = fmaf(v2, wv.x, a20); a21 = fmaf(v2, wv.y, a21);
            a22 = fmaf(v2, wv.z, a22); a23 = fmaf(v2, wv.w, a23);
            a30 = fmaf(v3, wv.x, a30); a31 = fmaf(v3, wv.y, a31);
            a32 = fmaf(v3, wv.z, a32); a33 = fmaf(v3, wv.w, a33);
        }
        float o[4][4] = {{a00, a01, a02, a03}, {a10, a11, a12, a13},
                         {a20, a21, a22, a23}, {a30, a31, a32, a33}};
#pragma unroll
        for (int q = 0; q < 4; ++q) {
            int row = r0 + rr + q;
            if (row >= N_NODES) break;
            float p0 = o[q][0], p1 = o[q][1], p2 = o[q][2], p3 = o[q][3];
            if (BIAS_RELU) {
                int cb = c * 4;
                p0 = fmaxf(p0 + bias[cb + 0], 0.f); p1 = fmaxf(p1 + bias[cb + 1], 0.f);
                p2 = fmaxf(p2 + bias[cb + 2], 0.f); p3 = fmaxf(p3 + bias[cb + 3], 0.f);
            }
            unsigned long long pv = (unsigned long long)bf16pack(p0, p1)
                                  | ((unsigned long long)bf16pack(p2, p3) << 32);
            Y[(size_t)kk * YST + sidx(c, row)] = pv;
            if (FUSE_STATS) {
                atomicAdd(&ls[c * 4 + 0], p0); atomicAdd(&ls[36 + c * 4 + 0], p0 * p0);
                atomicAdd(&ls[c * 4 + 1], p1); atomicAdd(&ls[36 + c * 4 + 1], p1 * p1);
                atomicAdd(&ls[c * 4 + 2], p2); atomicAdd(&ls[36 + c * 4 + 2], p2 * p2);
                atomicAdd(&ls[c * 4 + 3], p3); atomicAdd(&ls[36 + c * 4 + 3], p3 * p3);
            }
        }
    }
    if (FUSE_STATS) {
        __syncthreads();
        if (tid < 72) partials[(size_t)blockIdx.x * 72 + tid] = ls[tid];
    }
}

// ---------------- dual-row light gather step ----------------
// Each thread handles rows base+r and base+r+28 (56 rows/block) with
// interleaved 4+4 edge loops: doubles memory-level parallelism per thread
// (single-row deeper unroll is exhausted - R7).

template <int SCALE, bool WEIGHTED, bool HAS_B2, bool BIAS_RELU, bool FUSE_STATS>
__global__ __launch_bounds__(256) void gstep_kernel(
    const int* __restrict__ rp, const unsigned* __restrict__ csrc,
    const unsigned long long* __restrict__ INb, const unsigned long long* __restrict__ Yk,
    const unsigned long long* __restrict__ B2b, const float* __restrict__ bias,
    unsigned long long* __restrict__ OUT, float* __restrict__ partials) {
    __shared__ float ls[72];
    int tid = threadIdx.x;                       // 252 = 28 thread-rows x 9 lanes
    if (FUSE_STATS) { if (tid < 72) ls[tid] = 0.f; __syncthreads(); }
    int r = tid / 9, c = tid % 9;
    int rowA = blockIdx.x * 56 + r;
    int rowB = rowA + 28;
    bool vA = rowA < N_NODES, vB = rowB < N_NODES;
    const unsigned long long* gb = INb + ((c < 8) ? (size_t)c : (size_t)N_NODES * 8);
    int gsh = (c < 8) ? 3 : 0;
    float aAx = 0, aAy = 0, aAz = 0, aAw = 0;
    float bAx = 0, bAy = 0, bAz = 0, bAw = 0;
    float aBx = 0, aBy = 0, aBz = 0, aBw = 0;
    float bBx = 0, bBy = 0, bBz = 0, bBw = 0;
    int jA = 0, eA = 0, jB = 0, eB = 0;
    if (vA) { jA = rp[rowA]; eA = rp[rowA + 1]; }
    if (vB) { jB = rp[rowB]; eB = rp[rowB + 1]; }
    // interleaved main loop: 4 edges row A + 4 edges row B in flight
    while (jA + 3 < eA && jB + 3 < eB) {
        unsigned va0 = csrc[jA], va1 = csrc[jA + 1], va2 = csrc[jA + 2], va3 = csrc[jA + 3];
        unsigned vb0 = csrc[jB], vb1 = csrc[jB + 1], vb2 = csrc[jB + 2], vb3 = csrc[jB + 3];
        unsigned long long qa0 = gb[(size_t)esrc(va0) << gsh];
        unsigned long long qa1 = gb[(size_t)esrc(va1) << gsh];
        unsigned long long qa2 = gb[(size_t)esrc(va2) << gsh];
        unsigned long long qa3 = gb[(size_t)esrc(va3) << gsh];
        unsigned long long qb0 = gb[(size_t)esrc(vb0) << gsh];
        unsigned long long qb1 = gb[(size_t)esrc(vb1) << gsh];
        unsigned long long qb2 = gb[(size_t)esrc(vb2) << gsh];
        unsigned long long qb3 = gb[(size_t)esrc(vb3) << gsh];
        unsigned la0 = (unsigned)qa0, ha0 = (unsigned)(qa0 >> 32);
        unsigned la1 = (unsigned)qa1, ha1 = (unsigned)(qa1 >> 32);
        unsigned la2 = (unsigned)qa2, ha2 = (unsigned)(qa2 >> 32);
        unsigned la3 = (unsigned)qa3, ha3 = (unsigned)(qa3 >> 32);
        unsigned lb0 = (unsigned)qb0, hb0 = (unsigned)(qb0 >> 32);
        unsigned lb1 = (unsigned)qb1, hb1 = (unsigned)(qb1 >> 32);
        unsigned lb2 = (unsigned)qb2, hb2 = (unsigned)(qb2 >> 32);
        unsigned lb3 = (unsigned)qb3, hb3 = (unsigned)(qb3 >> 32);
        if (WEIGHTED) {
            float wa0 = ew(va0), wa1 = ew(va1), wa2 = ew(va2), wa3 = ew(va3);
            float wb0 = ew(vb0), wb1 = ew(vb1), wb2 = ew(vb2), wb3 = ew(vb3);
            aAx = fmaf(wa0, bflo(la0), aAx); aAy = fmaf(wa0, bfhi(la0), aAy);
            aAz = fmaf(wa0, bflo(ha0), aAz); aAw = fmaf(wa0, bfhi(ha0), aAw);
            bAx = fmaf(wa1, bflo(la1), bAx); bAy = fmaf(wa1, bfhi(la1), bAy);
            bAz = fmaf(wa1, bflo(ha1), bAz); bAw = fmaf(wa1, bfhi(ha1), bAw);
            aAx = fmaf(wa2, bflo(la2), aAx); aAy = fmaf(wa2, bfhi(la2), aAy);
            aAz = fmaf(wa2, bflo(ha2), aAz); aAw = fmaf(wa2, bfhi(ha2), aAw);
            bAx = fmaf(wa3, bflo(la3), bAx); bAy = fmaf(wa3, bfhi(la3), bAy);
            bAz = fmaf(wa3, bflo(ha3), bAz); bAw = fmaf(wa3, bfhi(ha3), bAw);
            aBx = fmaf(wb0, bflo(lb0), aBx); aBy = fmaf(wb0, bfhi(lb0), aBy);
            aBz = fmaf(wb0, bflo(hb0), aBz); aBw = fmaf(wb0, bfhi(hb0), aBw);
            bBx = fmaf(wb1, bflo(lb1), bBx); bBy = fmaf(wb1, bfhi(lb1), bBy);
            bBz = fmaf(wb1, bflo(hb1), bBz); bBw = fmaf(wb1, bfhi(hb1), bBw);
            aBx = fmaf(wb2, bflo(lb2), aBx); aBy = fmaf(wb2, bfhi(lb2), aBy);
            aBz = fmaf(wb2, bflo(hb2), aBz); aBw = fmaf(wb2, bfhi(hb2), aBw);
            bBx = fmaf(wb3, bflo(lb3), bBx); bBy = fmaf(wb3, bfhi(lb3), bBy);
            bBz = fmaf(wb3, bflo(hb3), bBz); bBw = fmaf(wb3, bfhi(hb3), bBw);
        } else {
            aAx += bflo(la0) + bflo(la2); aAy += bfhi(la0) + bfhi(la2);
            aAz += bflo(ha0) + bflo(ha2); aAw += bfhi(ha0) + bfhi(ha2);
            bAx += bflo(la1) + bflo(la3); bAy += bfhi(la1) + bfhi(la3);
            bAz += bflo(ha1) + bflo(ha3); bAw += bfhi(ha1) + bfhi(ha3);
            aBx += bflo(lb0) + bflo(lb2); aBy += bfhi(lb0) + bfhi(lb2);
            aBz += bflo(hb0) + bflo(hb2); aBw += bfhi(hb0) + bfhi(hb2);
            bBx += bflo(lb1) + bflo(lb3); bBy += bfhi(lb1) + bfhi(lb3);
            bBz += bflo(hb1) + bflo(hb3); bBw += bfhi(hb1) + bfhi(hb3);
        }
        jA += 4; jB += 4;
    }
    // drain row A
    for (; jA + 3 < eA; jA += 4) {
        unsigned v0 = csrc[jA], v1 = csrc[jA + 1], v2 = csrc[jA + 2], v3 = csrc[jA + 3];
        unsigned long long q0 = gb[(size_t)esrc(v0) << gsh];
        unsigned long long q1 = gb[(size_t)esrc(v1) << gsh];
        unsigned long long q2 = gb[(size_t)esrc(v2) << gsh];
        unsigned long long q3 = gb[(size_t)esrc(v3) << gsh];
        unsigned l0 = (unsigned)q0, h0 = (unsigned)(q0 >> 32);
        unsigned l1 = (unsigned)q1, h1 = (unsigned)(q1 >> 32);
        unsigned l2 = (unsigned)q2, h2 = (unsigned)(q2 >> 32);
        unsigned l3 = (unsigned)q3, h3 = (unsigned)(q3 >> 32);
        if (WEIGHTED) {
            float w0 = ew(v0), w1 = ew(v1), w2 = ew(v2), w3 = ew(v3);
            aAx = fmaf(w0, bflo(l0), aAx); aAy = fmaf(w0, bfhi(l0), aAy);
            aAz = fmaf(w0, bflo(h0), aAz); aAw = fmaf(w0, bfhi(h0), aAw);
            bAx = fmaf(w1, bflo(l1), bAx); bAy = fmaf(w1, bfhi(l1), bAy);
            bAz = fmaf(w1, bflo(h1), bAz); bAw = fmaf(w1, bfhi(h1), bAw);
            aAx = fmaf(w2, bflo(l2), aAx); aAy = fmaf(w2, bfhi(l2), aAy);
            aAz = fmaf(w2, bflo(h2), aAz); aAw = fmaf(w2, bfhi(h2), aAw);
            bAx = fmaf(w3, bflo(l3), bAx); bAy = fmaf(w3, bfhi(l3), bAy);
            bAz = fmaf(w3, bflo(h3), bAz); bAw = fmaf(w3, bfhi(h3), bAw);
        } else {
            aAx += bflo(l0) + bflo(l2); aAy += bfhi(l0) + bfhi(l2);
            aAz += bflo(h0) + bflo(h2); aAw += bfhi(h0) + bfhi(h2);
            bAx += bflo(l1) + bflo(l3); bAy += bfhi(l1) + bfhi(l3);
            bAz += bflo(h1) + bflo(h3); bAw += bfhi(h1) + bfhi(h3);
        }
    }
    for (; jA < eA; ++jA) {
        unsigned v = csrc[jA];
        unsigned long long q = gb[(size_t)esrc(v) << gsh];
        unsigned l = (unsigned)q, h = (unsigned)(q >> 32);
        if (WEIGHTED) {
            float w = ew(v);
            aAx = fmaf(w, bflo(l), aAx); aAy = fmaf(w, bfhi(l), aAy);
            aAz = fmaf(w, bflo(h), aAz); aAw = fmaf(w, bfhi(h), aAw);
        } else {
            aAx += bflo(l); aAy += bfhi(l);
            aAz += bflo(h); aAw += bfhi(h);
        }
    }
    // drain row B
    for (; jB + 3 < eB; jB += 4) {
        unsigned v0 = csrc[jB], v1 = csrc[jB + 1], v2 = csrc[jB + 2], v3 = csrc[jB + 3];
        unsigned long long q0 = gb[(size_t)esrc(v0) << gsh];
        unsigned long long q1 = gb[(size_t)esrc(v1) << gsh];
        unsigned long long q2 = gb[(size_t)esrc(v2) << gsh];
        unsigned long long q3 = gb[(size_t)esrc(v3) << gsh];
        unsigned l0 = (unsigned)q0, h0 = (unsigned)(q0 >> 32);
        unsigned l1 = (unsigned)q1, h1 = (unsigned)(q1 >> 32);
        unsigned l2 = (unsigned)q2, h2 = (unsigned)(q2 >> 32);
        unsigned l3 = (unsigned)q3, h3 = (unsigned)(q3 >> 32);
        if (WEIGHTED) {
            float w0 = ew(v0), w1 = ew(v1), w2 = ew(v2), w3 = ew(v3);
            aBx = fmaf(w0, bflo(l0), aBx); aBy = fmaf(w0, bfhi(l0), aBy);
            aBz = fmaf(w0, bflo(h0), aBz); aBw = fmaf(w0, bfhi(h0), aBw);
            bBx = fmaf(w1, bflo(l1), bBx); bBy = fmaf(w1, bfhi(l1), bBy);
            bBz = fmaf(w1, bflo(h1), bBz); bBw = fmaf(w1, bfhi(h1), bBw);
            aBx = fmaf(w2, bflo(l2), aBx); aBy = fmaf(w2, bfhi(l2), aBy);
            aBz = fmaf(w2, bflo(h2), aBz); aBw = fmaf(w2, bfhi(h2), aBw);
            bBx = fmaf(w3, bflo(l3), bBx); bBy = fmaf(w3, bfhi(l3), bBy);
            bBz = fmaf(w3, bflo(h3), bBz); bBw = fmaf(w3, bfhi(h3), bBw);
        } else {
            aBx += bflo(l0) + bflo(l2); aBy += bfhi(l0) + bfhi(l2);
            aBz += bflo(h0) + bflo(h2); aBw += bfhi(h0) + bfhi(h2);
            bBx += bflo(l1) + bflo(l3); bBy += bfhi(l1) + bfhi(l3);
            bBz += bflo(h1) + bflo(h3); bBw += bfhi(h1) + bfhi(h3);
        }
    }
    for (; jB < eB; ++jB) {
        unsigned v = csrc[jB];
        unsigned long long q = gb[(size_t)esrc(v) << gsh];
        unsigned l = (unsigned)q, h = (unsigned)(q >> 32);
        if (WEIGHTED) {
            float w = ew(v);
            aBx = fmaf(w, bflo(l), aBx); aBy = fmaf(w, bfhi(l), aBy);
            aBz = fmaf(w, bflo(h), aBz); aBw = fmaf(w, bfhi(h), aBw);
        } else {
            aBx += bflo(l); aBy += bfhi(l);
            aBz += bflo(h); aBw += bfhi(h);
        }
    }
    const float S = (float)SCALE;
    auto epi = [&](int row, float ax, float ay, float az, float aw) {
        unsigned long long qy = Yk[sidx(c, row)];
        unsigned ly = (unsigned)qy, hy = (unsigned)(qy >> 32);
        float ox = fmaf(S, ax, bflo(ly)), oy = fmaf(S, ay, bfhi(ly));
        float oz = fmaf(S, az, bflo(hy)), ow = fmaf(S, aw, bfhi(hy));
        if (HAS_B2) {
            unsigned long long qb = B2b[sidx(c, row)];
            unsigned lb = (unsigned)qb, hb = (unsigned)(qb >> 32);
            ox -= bflo(lb); oy -= bfhi(lb);
            oz -= bflo(hb); ow -= bfhi(hb);
        }
        if (BIAS_RELU) {
            int cb = c * 4;
            ox = fmaxf(ox + bias[cb + 0], 0.f); oy = fmaxf(oy + bias[cb + 1], 0.f);
            oz = fmaxf(oz + bias[cb + 2], 0.f); ow = fmaxf(ow + bias[cb + 3], 0.f);
        }
        unsigned long long pv = (unsigned long long)bf16pack(ox, oy)
                              | ((unsigned long long)bf16pack(oz, ow) << 32);
        OUT[sidx(c, row)] = pv;
        if (FUSE_STATS) {
            atomicAdd(&ls[c * 4 + 0], ox); atomicAdd(&ls[36 + c * 4 + 0], ox * ox);
            atomicAdd(&ls[c * 4 + 1], oy); atomicAdd(&ls[36 + c * 4 + 1], oy * oy);
            atomicAdd(&ls[c * 4 + 2], oz); atomicAdd(&ls[36 + c * 4 + 2], oz * oz);
            atomicAdd(&ls[c * 4 + 3], ow); atomicAdd(&ls[36 + c * 4 + 3], ow * ow);
        }
    };
    if (vA) epi(rowA, aAx + bAx, aAy + bAy, aAz + bAz, aAw + bAw);
    if (vB) epi(rowB, aBx + bBx, aBy + bBy, aBz + bBz, aBw + bBw);
    if (FUSE_STATS) {
        __syncthreads();
        if (tid < 72) partials[(size_t)blockIdx.x * 72 + tid] = ls[tid];
    }
}

// ---------------- finalize: reduce partials -> BN scale/shift ----------------

__global__ __launch_bounds__(256) void finalize_kernel(
    const float* __restrict__ partials, int nb, const float* __restrict__ g,
    const float* __restrict__ be, float* __restrict__ ss) {
    __shared__ float rs[256], rq[256];
    int c = blockIdx.x;
    int t = threadIdx.x;
    float s = 0.f, q = 0.f;
    for (int i = t; i < nb; i += 256) {
        s += partials[(size_t)i * 72 + c];
        q += partials[(size_t)i * 72 + c + 36];
    }
    rs[t] = s; rq[t] = q;
    __syncthreads();
    for (int off = 128; off > 0; off >>= 1) {
        if (t < off) { rs[t] += rs[t + off]; rq[t] += rq[t + off]; }
        __syncthreads();
    }
    if (t == 0) {
        float m = rs[0] / (float)N_NODES;
        float v = rq[0] / (float)N_NODES - m * m;
        float sc = g[c] * rsqrtf(v + 1e-5f);
        ss[c] = sc;
        ss[36 + c] = be[c] - m * sc;
    }
}

// ---------------- final concat GEMM, split-layout bf16 inputs (32 rows/block) ----

__global__ __launch_bounds__(256) void fused3_kernel(
    const unsigned long long* __restrict__ X1b, const float* __restrict__ ssA,
    const unsigned long long* __restrict__ X2b, const float* __restrict__ ssB,
    const unsigned long long* __restrict__ X3b, const float* __restrict__ ssC,
    const float* __restrict__ W, const float* __restrict__ b,
    float* __restrict__ out) {
    __shared__ float Wl[108 * 32];
    __shared__ float Al[32][109];
    int tid = threadIdx.x;
    for (int i = tid; i < 108 * 32; i += 256) Wl[i] = W[i];
    int r0 = blockIdx.x * 32;
    for (int i = tid; i < 32 * 108; i += 256) {
        int r = i / 108, f = i % 108;
        int row = r0 + r;
        float v = 0.f;
        if (row < N_NODES) {
            int t = f / 36, ff = f % 36;
            const unsigned short* b16 =
                (const unsigned short*)(t == 0 ? X1b : (t == 1 ? X2b : X3b));
            unsigned short u16 = (ff < 32)
                ? b16[(size_t)row * 32 + ff]
                : b16[(size_t)N_NODES * 32 + (size_t)row * 4 + (ff - 32)];
            float xv = __uint_as_float((unsigned)u16 << 16);
            if (t == 0)      v = fmaxf(fmaf(ssA[ff], xv, ssA[36 + ff]), 0.f);
            else if (t == 1) v = fmaxf(fmaf(ssB[ff], xv, ssB[36 + ff]), 0.f);
            else             v = fmaf(ssC[ff], xv, ssC[36 + ff]);
        }
        Al[r][f] = v;
    }
    __syncthreads();
    int r = tid >> 3, q = tid & 7;
    int row = r0 + r;
    if (row >= N_NODES) return;
    float acc[4];
#pragma unroll
    for (int j = 0; j < 4; ++j) acc[j] = b[q * 4 + j];
    for (int f = 0; f < 108; ++f) {
        float a = Al[r][f];
#pragma unroll
        for (int j = 0; j < 4; ++j)
            acc[j] = fmaf(a, Wl[f * 32 + q * 4 + j], acc[j]);
    }
#pragma unroll
    for (int j = 0; j < 4; ++j) out[(size_t)row * 32 + q * 4 + j] = acc[j];
}

// ---------------- launch ----------------

extern "C" void kernel_launch(void* const* d_in, const int* in_sizes, int n_in,
                              void* d_out, int out_size, void* d_ws, size_t ws_size,
                              hipStream_t stream) {
    const float* x      = (const float*)d_in[0];
    const int*   ei     = (const int*)d_in[1];
    const float* W1_1   = (const float*)d_in[2];
    // b1_1 / b1_2 cancel exactly under training-mode BN -> dropped.
    const float* g1_1   = (const float*)d_in[4];
    const float* be1_1  = (const float*)d_in[5];
    const float* W1_2   = (const float*)d_in[6];
    const float* g1_2   = (const float*)d_in[8];
    const float* be1_2  = (const float*)d_in[9];
    const float* gin_w1 = (const float*)d_in[10];
    const float* gin_b1 = (const float*)d_in[11];
    const float* gin_w2 = (const float*)d_in[12];
    const float* gin_b2 = (const float*)d_in[13];
    const float* g2     = (const float*)d_in[14];
    const float* be2    = (const float*)d_in[15];
    const float* W4     = (const float*)d_in[16];
    const float* b4     = (const float*)d_in[17];
    float* out = (float*)d_out;

    char* ws = (char*)d_ws;
    size_t off = 0;
    auto alloc = [&](size_t bytes) -> char* {
        char* p = ws + off;
        off = (off + bytes + 255) & ~(size_t)255;
        return p;
    };
    int*   rp    = (int*)alloc((size_t)(N_NODES + 1) * 4);
    unsigned* csrc = (unsigned*)alloc((size_t)N_EDGES * 4);
    float* ssA   = (float*)alloc(72 * 4);
    float* ssB   = (float*)alloc(72 * 4);
    float* ssC   = (float*)alloc(72 * 4);
    float* partials = (float*)alloc((size_t)6250 * 72 * 4);
    uint2* xbf = (uint2*)alloc((size_t)N_NODES * 128);     // bf16 [N,64] 128B rows
    // Y region: 9 split-buffers (64.8MB); preproc temps carved inside (dead after)
    char*  U = alloc(9 * YST * 8);
    unsigned long long* Yall = (unsigned long long*)U;
    constexpr size_t NBBF = (size_t)N_NODES * 72;
    unsigned long long* R0  = (unsigned long long*)alloc(NBBF);
    unsigned long long* R1  = (unsigned long long*)alloc(NBBF);
    unsigned long long* R2  = (unsigned long long*)alloc(NBBF);
    unsigned long long* X1b = (unsigned long long*)alloc(NBBF);
    unsigned long long* X2b = (unsigned long long*)alloc(NBBF);
    unsigned long long* X3b = (unsigned long long*)alloc(NBBF);
    if (off > ws_size) return;

    // preproc temps inside U
    int*   cntD = (int*)U;
    int*   cntS = cntD + LCNT;
    int*   bsum = cntS + LCNT;
    float* dis  = (float*)(bsum + 1024);
    int2*  edgepart = (int2*)(dis + N_NODES);
    int*   srcpart  = (int*)(edgepart + N_EDGES);

    part_count_kernel<<<NBLK, 256, 0, stream>>>(ei, cntD, cntS);
    scanA_kernel<<<SCAN_BLKS, 256, 0, stream>>>(cntD, cntD, bsum, LCNT);
    scanB_kernel<<<1, 1024, 0, stream>>>(bsum, SCAN_BLKS);
    scanC_kernel<<<SCAN_BLKS, 256, 0, stream>>>(cntD, bsum, LCNT);
    scanA_kernel<<<SCAN_BLKS, 256, 0, stream>>>(cntS, cntS, bsum, LCNT);
    scanB_kernel<<<1, 1024, 0, stream>>>(bsum, SCAN_BLKS);
    scanC_kernel<<<SCAN_BLKS, 256, 0, stream>>>(cntS, bsum, LCNT);
    part_scatter_kernel<<<NBLK, 256, 0, stream>>>(ei, cntD, cntS, edgepart, srcpart);
    deg_kernel<<<NBK, 256, 0, stream>>>(srcpart, cntS, dis);
    csr_kernel<<<NBK, 256, 0, stream>>>(edgepart, cntD, dis, rp, csrc);
    pack_x_kernel<<<(N_NODES * 16 + 255) / 256, 256, 0, stream>>>(x, xbf);

    const int GBLKS = (N_NODES + 55) / 56;     // 1786 (dual-row gsteps)
    const int PBLKS = (N_NODES + 111) / 112;   // 893  (batchproj row-blocks)
    const int F3_BLKS = (N_NODES + 31) / 32;   // 3125
    const unsigned long long* xb64 = (const unsigned long long*)xbf;
    auto Y = [&](int k) { return Yall + (size_t)k * YST; };

    // ---- conv1_1: batched proj (9 kk over 3 chunks), then 7 light steps ----
    batchproj_kernel<64, 8, 3, false, true, false, false><<<PBLKS * 3, 252, 0, stream>>>(
        xb64, W1_1, gin_w1, nullptr, nullptr, Yall, nullptr, PBLKS);
    gstep_kernel<2, true, false, false, false><<<GBLKS, 252, 0, stream>>>(
        rp, csrc, Y(7), Y(6), nullptr, nullptr, R0, nullptr);
    gstep_kernel<2, true, true, false, false><<<GBLKS, 252, 0, stream>>>(
        rp, csrc, R0, Y(5), Y(7), nullptr, R1, nullptr);
    gstep_kernel<2, true, true, false, false><<<GBLKS, 252, 0, stream>>>(
        rp, csrc, R1, Y(4), R0, nullptr, R2, nullptr);
    gstep_kernel<2, true, true, false, false><<<GBLKS, 252, 0, stream>>>(
        rp, csrc, R2, Y(3), R1, nullptr, R0, nullptr);
    gstep_kernel<2, true, true, false, false><<<GBLKS, 252, 0, stream>>>(
        rp, csrc, R0, Y(2), R2, nullptr, R1, nullptr);
    gstep_kernel<2, true, true, false, false><<<GBLKS, 252, 0, stream>>>(
        rp, csrc, R1, Y(1), R0, nullptr, R2, nullptr);
    gstep_kernel<1, true, true, false, true><<<GBLKS, 252, 0, stream>>>(
        rp, csrc, R2, Y(0), R1, nullptr, X1b, partials);
    finalize_kernel<<<36, 256, 0, stream>>>(partials, GBLKS, g1_1, be1_1, ssA);

    // ---- GIN: m1 = relu(Y8_self + sum Y8_src + b1) -> R0; X3 = relu(m1@w2+b2)+stats ----
    gstep_kernel<1, false, false, true, false><<<GBLKS, 252, 0, stream>>>(
        rp, csrc, Y(8), Y(8), nullptr, gin_b1, R0, nullptr);
    batchproj_kernel<36, 1, 1, false, false, true, true><<<PBLKS, 252, 0, stream>>>(
        R0, gin_w2, nullptr, nullptr, gin_b2, X3b, partials, PBLKS);
    finalize_kernel<<<36, 256, 0, stream>>>(partials, PBLKS, g2, be2, ssC);

    // ---- conv1_2: batched proj of bn(X1b) (8 kk over 3 chunks), then 7 steps ----
    batchproj_kernel<36, 8, 3, true, false, false, false><<<PBLKS * 3, 252, 0, stream>>>(
        X1b, W1_2, nullptr, ssA, nullptr, Yall, nullptr, PBLKS);
    gstep_kernel<2, true, false, false, false><<<GBLKS, 252, 0, stream>>>(
        rp, csrc, Y(7), Y(6), nullptr, nullptr, R0, nullptr);
    gstep_kernel<2, true, true, false, false><<<GBLKS, 252, 0, stream>>>(
        rp, csrc, R0, Y(5), Y(7), nullptr, R1, nullptr);
    gstep_kernel<2, true, true, false, false><<<GBLKS, 252, 0, stream>>>(
        rp, csrc, R1, Y(4), R0, nullptr, R2, nullptr);
    gstep_kernel<2, true, true, false, false><<<GBLKS, 252, 0, stream>>>(
        rp, csrc, R2, Y(3), R1, nullptr, R0, nullptr);
    gstep_kernel<2, true, true, false, false><<<GBLKS, 252, 0, stream>>>(
        rp, csrc, R0, Y(2), R2, nullptr, R1, nullptr);
    gstep_kernel<2, true, true, false, false><<<GBLKS, 252, 0, stream>>>(
        rp, csrc, R1, Y(1), R0, nullptr, R2, nullptr);
    gstep_kernel<1, true, true, false, true><<<GBLKS, 252, 0, stream>>>(
        rp, csrc, R2, Y(0), R1, nullptr, X2b, partials);
    finalize_kernel<<<36, 256, 0, stream>>>(partials, GBLKS, g1_2, be1_2, ssB);

    // ---- final concat GEMM ----
    fused3_kernel<<<F3_BLKS, 256, 0, stream>>>(X1b, ssA, X2b, ssB, X3b, ssC, W4, b4, out);
}

// Round 21
// 862.109 us; speedup vs baseline: 1.0127x; 1.0127x over previous
//
#include <hip/hip_runtime.h>

constexpr int N_NODES = 100000;
constexpr int N_EDGES = 1600000;
constexpr int NBK  = 391;
constexpr int NBLK = 640;
constexpr int CHUNK = 2500;
constexpr int LCNT = NBK * NBLK;
constexpr int SCAN_BLKS = (LCNT + 255) / 256;
constexpr size_t YST = (size_t)N_NODES * 9;   // u64 per 36-col split buffer

// ---------------- bf16 helpers (RNE) ----------------

__device__ __forceinline__ unsigned bf16pack(float a, float b) {
    unsigned ua = __float_as_uint(a), ub = __float_as_uint(b);
    ua += 0x7fffu + ((ua >> 16) & 1u);
    ub += 0x7fffu + ((ub >> 16) & 1u);
    return (ua >> 16) | (ub & 0xffff0000u);
}
__device__ __forceinline__ float bflo(unsigned p) { return __uint_as_float(p << 16); }
__device__ __forceinline__ float bfhi(unsigned p) { return __uint_as_float(p & 0xffff0000u); }

// packed edge: bits 0..16 = src; bits 17..31 = 15-bit weight (implicit negative)
__device__ __forceinline__ int esrc(unsigned v) { return (int)(v & 0x1FFFFu); }
__device__ __forceinline__ float ew(unsigned v) {
    return __uint_as_float(0x80000000u | ((v >> 17) << 16));
}

// Split bf16 36-col buffer: A-region [N][8 u64] (cols 0..31, 64B rows),
// B-region [N][1 u64] (cols 32..35) at u64 offset N*8. Lane c in 0..8.
__device__ __forceinline__ size_t sidx(int c, int row) {
    return (c < 8) ? ((size_t)row * 8 + c) : ((size_t)N_NODES * 8 + row);
}

// ---------------- preprocessing (proven, unchanged) ----------------

__global__ __launch_bounds__(256) void part_count_kernel(
    const int* __restrict__ ei, int* __restrict__ cntD, int* __restrict__ cntS) {
    __shared__ int hd[NBK], hs[NBK];
    int tid = threadIdx.x;
    for (int i = tid; i < NBK; i += 256) { hd[i] = 0; hs[i] = 0; }
    __syncthreads();
    int e0 = blockIdx.x * CHUNK;
    for (int e = e0 + tid; e < e0 + CHUNK; e += 256) {
        int s = ei[e], d = ei[N_EDGES + e];
        atomicAdd(&hs[s >> 8], 1);
        atomicAdd(&hd[d >> 8], 1);
    }
    __syncthreads();
    for (int i = tid; i < NBK; i += 256) {
        cntD[i * NBLK + blockIdx.x] = hd[i];
        cntS[i * NBLK + blockIdx.x] = hs[i];
    }
}

__global__ __launch_bounds__(256) void scanA_kernel(const int* __restrict__ in,
                                                    int* __restrict__ out,
                                                    int* __restrict__ bsum, int L) {
    __shared__ int sm[256];
    int i = blockIdx.x * 256 + threadIdx.x;
    int v = (i < L) ? in[i] : 0;
    sm[threadIdx.x] = v;
    __syncthreads();
    for (int off = 1; off < 256; off <<= 1) {
        int t = (threadIdx.x >= off) ? sm[threadIdx.x - off] : 0;
        __syncthreads();
        sm[threadIdx.x] += t;
        __syncthreads();
    }
    if (i < L) out[i] = sm[threadIdx.x] - v;
    if (threadIdx.x == 255) bsum[blockIdx.x] = sm[255];
}

__global__ __launch_bounds__(1024) void scanB_kernel(int* __restrict__ bsum, int nb) {
    __shared__ int sm[1024];
    int t = threadIdx.x;
    int v = (t < nb) ? bsum[t] : 0;
    sm[t] = v;
    __syncthreads();
    for (int off = 1; off < 1024; off <<= 1) {
        int u = (t >= off) ? sm[t - off] : 0;
        __syncthreads();
        sm[t] += u;
        __syncthreads();
    }
    if (t < nb) bsum[t] = sm[t] - v;
}

__global__ __launch_bounds__(256) void scanC_kernel(int* __restrict__ out,
                                                    const int* __restrict__ bsum, int L) {
    int i = blockIdx.x * 256 + threadIdx.x;
    if (i < L) out[i] += bsum[blockIdx.x];
}

__global__ __launch_bounds__(256) void part_scatter_kernel(
    const int* __restrict__ ei, const int* __restrict__ scanD,
    const int* __restrict__ scanS, int2* __restrict__ edgepart,
    int* __restrict__ srcpart) {
    __shared__ int curD[NBK], curS[NBK];
    int tid = threadIdx.x;
    for (int i = tid; i < NBK; i += 256) {
        curD[i] = scanD[i * NBLK + blockIdx.x];
        curS[i] = scanS[i * NBLK + blockIdx.x];
    }
    __syncthreads();
    int e0 = blockIdx.x * CHUNK;
    for (int e = e0 + tid; e < e0 + CHUNK; e += 256) {
        int s = ei[e], d = ei[N_EDGES + e];
        int pd = atomicAdd(&curD[d >> 8], 1);
        edgepart[pd] = make_int2(s, d);
        int ps = atomicAdd(&curS[s >> 8], 1);
        srcpart[ps] = s;
    }
}

__global__ __launch_bounds__(256) void deg_kernel(const int* __restrict__ srcpart,
                                                  const int* __restrict__ scanS,
                                                  float* __restrict__ dis) {
    __shared__ int cnt[256];
    int b = blockIdx.x, tid = threadIdx.x;
    cnt[tid] = 0;
    __syncthreads();
    int beg = scanS[b * NBLK];
    int end = (b + 1 < NBK) ? scanS[(b + 1) * NBLK] : N_EDGES;
    for (int j = beg + tid; j < end; j += 256)
        atomicAdd(&cnt[srcpart[j] & 255], 1);
    __syncthreads();
    int node = b * 256 + tid;
    if (node < N_NODES) dis[node] = cnt[tid] > 0 ? rsqrtf((float)cnt[tid]) : 0.f;
}

__global__ __launch_bounds__(256) void csr_kernel(const int2* __restrict__ edgepart,
                                                  const int* __restrict__ scanD,
                                                  const float* __restrict__ dis,
                                                  int* __restrict__ rp,
                                                  unsigned* __restrict__ csrc) {
    __shared__ int cnt[256];
    __shared__ int lofs[256];
    __shared__ float disl[256];
    int b = blockIdx.x, tid = threadIdx.x;
    int beg = scanD[b * NBLK];
    int end = (b + 1 < NBK) ? scanD[(b + 1) * NBLK] : N_EDGES;
    int node = b * 256 + tid;
    cnt[tid] = 0;
    disl[tid] = (node < N_NODES) ? dis[node] : 0.f;
    __syncthreads();
    for (int j = beg + tid; j < end; j += 256)
        atomicAdd(&cnt[edgepart[j].y & 255], 1);
    __syncthreads();
    int v = cnt[tid];
    lofs[tid] = v;
    __syncthreads();
    for (int off = 1; off < 256; off <<= 1) {
        int t = (tid >= off) ? lofs[tid - off] : 0;
        __syncthreads();
        lofs[tid] += t;
        __syncthreads();
    }
    int myexc = lofs[tid] - v;
    if (node < N_NODES) rp[node] = beg + myexc;
    if (b == NBK - 1 && tid == 0) rp[N_NODES] = N_EDGES;
    __syncthreads();
    lofs[tid] = myexc;
    cnt[tid] = 0;
    __syncthreads();
    for (int j = beg + tid; j < end; j += 256) {
        int2 e = edgepart[j];
        int dl = e.y & 255;
        int pos = beg + lofs[dl] + atomicAdd(&cnt[dl], 1);
        unsigned u = __float_as_uint(-(dis[e.x] * disl[dl]));
        u += 0x7fffu + ((u >> 16) & 1u);
        unsigned wb = (u >> 16) & 0x7FFFu;
        csrc[pos] = (unsigned)e.x | (wb << 17);
    }
}

// pack x [N,64] f32 -> bf16 row-major (16 u64 = 128B rows)
__global__ void pack_x_kernel(const float* __restrict__ x, uint2* __restrict__ xbf) {
    int i = blockIdx.x * blockDim.x + threadIdx.x;
    if (i >= N_NODES * 16) return;
    float4 v = ((const float4*)x)[i];
    xbf[i] = make_uint2(bf16pack(v.x, v.y), bf16pack(v.z, v.w));
}

// ---------------- batched projection, 4x4 reg tiles, kk-chunked grid ----------

template <int FI, int NK, int KPB, bool BN_A, bool EXTRA, bool BIAS_RELU, bool FUSE_STATS>
__global__ __launch_bounds__(256) void batchproj_kernel(
    const unsigned long long* __restrict__ Ab, const float* __restrict__ W,
    const float* __restrict__ Wx, const float* __restrict__ ss,
    const float* __restrict__ bias, unsigned long long* __restrict__ Y,
    float* __restrict__ partials, int pblks) {
    constexpr int RU2 = FI / 4;
    constexpr int NKT = NK + (EXTRA ? 1 : 0);
    __shared__ float Wl[FI * 36];
    __shared__ float Atile[112][FI + 1];
    __shared__ float ls[72];
    int tid = threadIdx.x;                       // 252 = 28 row-groups x 9 lanes
    int blk = blockIdx.x % pblks;
    int kk0 = (blockIdx.x / pblks) * KPB;
    int kk1 = min(kk0 + KPB, NKT);
    int r0 = blk * 112;
    for (int i = tid; i < 112 * RU2; i += 252) {
        int r = i / RU2, u = i % RU2;
        int row = r0 + r;
        long long av = 0;
        if (row < N_NODES) {
            size_t idx = (FI == 64) ? ((size_t)row * 16 + u) : sidx(u, row);
            av = (long long)Ab[idx];
        }
        unsigned lo = (unsigned)av, hi = (unsigned)(av >> 32);
        float f0 = bflo(lo), f1 = bfhi(lo), f2 = bflo(hi), f3 = bfhi(hi);
        if (BN_A) {
            int f = u * 4;
            f0 = fmaxf(fmaf(ss[f + 0], f0, ss[36 + f + 0]), 0.f);
            f1 = fmaxf(fmaf(ss[f + 1], f1, ss[36 + f + 1]), 0.f);
            f2 = fmaxf(fmaf(ss[f + 2], f2, ss[36 + f + 2]), 0.f);
            f3 = fmaxf(fmaf(ss[f + 3], f3, ss[36 + f + 3]), 0.f);
        }
        Atile[r][u * 4 + 0] = f0; Atile[r][u * 4 + 1] = f1;
        Atile[r][u * 4 + 2] = f2; Atile[r][u * 4 + 3] = f3;
    }
    if (FUSE_STATS && tid < 72) ls[tid] = 0.f;
    int g = tid / 9, c = tid % 9;
    int rr = 4 * g;
    for (int kk = kk0; kk < kk1; ++kk) {
        const float* Wk = (EXTRA && kk == NK) ? Wx : (W + (size_t)kk * FI * 36);
        __syncthreads();
        for (int i = tid; i < FI * 36; i += 252) Wl[i] = Wk[i];
        __syncthreads();
        float a00 = 0, a01 = 0, a02 = 0, a03 = 0;
        float a10 = 0, a11 = 0, a12 = 0, a13 = 0;
        float a20 = 0, a21 = 0, a22 = 0, a23 = 0;
        float a30 = 0, a31 = 0, a32 = 0, a33 = 0;
        const float4* Wl4 = (const float4*)Wl;
#pragma unroll 4
        for (int f = 0; f < FI; ++f) {
            float4 wv = Wl4[f * 9 + c];
            float v0 = Atile[rr + 0][f];
            float v1 = Atile[rr + 1][f];
            float v2 = Atile[rr + 2][f];
            float v3 = Atile[rr + 3][f];
            a00 = fmaf(v0, wv.x, a00); a01 = fmaf(v0, wv.y, a01);
            a02 = fmaf(v0, wv.z, a02); a03 = fmaf(v0, wv.w, a03);
            a10 = fmaf(v1, wv.x, a10); a11 = fmaf(v1, wv.y, a11);
            a12 = fmaf(v1, wv.z, a12); a13 = fmaf(v1, wv.w, a13);
            a20 = fmaf(v2, wv.x, a20); a21 = fmaf(v2, wv.y, a21);
            a22 = fmaf(v2, wv.z, a22); a23 = fmaf(v2, wv.w, a23);
            a30 = fmaf(v3, wv.x, a30); a31 = fmaf(v3, wv.y, a31);
            a32 = fmaf(v3, wv.z, a32); a33 = fmaf(v3, wv.w, a33);
        }
        float o[4][4] = {{a00, a01, a02, a03}, {a10, a11, a12, a13},
                         {a20, a21, a22, a23}, {a30, a31, a32, a33}};
#pragma unroll
        for (int q = 0; q < 4; ++q) {
            int row = r0 + rr + q;
            if (row >= N_NODES) break;
            float p0 = o[q][0], p1 = o[q][1], p2 = o[q][2], p3 = o[q][3];
            if (BIAS_RELU) {
                int cb = c * 4;
                p0 = fmaxf(p0 + bias[cb + 0], 0.f); p1 = fmaxf(p1 + bias[cb + 1], 0.f);
                p2 = fmaxf(p2 + bias[cb + 2], 0.f); p3 = fmaxf(p3 + bias[cb + 3], 0.f);
            }
            unsigned long long pv = (unsigned long long)bf16pack(p0, p1)
                                  | ((unsigned long long)bf16pack(p2, p3) << 32);
            Y[(size_t)kk * YST + sidx(c, row)] = pv;
            if (FUSE_STATS) {
                atomicAdd(&ls[c * 4 + 0], p0); atomicAdd(&ls[36 + c * 4 + 0], p0 * p0);
                atomicAdd(&ls[c * 4 + 1], p1); atomicAdd(&ls[36 + c * 4 + 1], p1 * p1);
                atomicAdd(&ls[c * 4 + 2], p2); atomicAdd(&ls[36 + c * 4 + 2], p2 * p2);
                atomicAdd(&ls[c * 4 + 3], p3); atomicAdd(&ls[36 + c * 4 + 3], p3 * p3);
            }
        }
    }
    if (FUSE_STATS) {
        __syncthreads();
        if (tid < 72) partials[(size_t)blockIdx.x * 72 + tid] = ls[tid];
    }
}

// ---------------- light gather step (no A-stream, no staging) ----------------

template <int SCALE, bool WEIGHTED, bool HAS_B2, bool BIAS_RELU, bool FUSE_STATS>
__global__ __launch_bounds__(256) void gstep_kernel(
    const int* __restrict__ rp, const unsigned* __restrict__ csrc,
    const unsigned long long* __restrict__ INb, const unsigned long long* __restrict__ Yk,
    const unsigned long long* __restrict__ B2b, const float* __restrict__ bias,
    unsigned long long* __restrict__ OUT, float* __restrict__ partials) {
    __shared__ float ls[72];
    int tid = threadIdx.x;                       // 252 = 28 rows x 9 lanes
    if (FUSE_STATS) { if (tid < 72) ls[tid] = 0.f; __syncthreads(); }
    int r = tid / 9, c = tid % 9;
    int row = blockIdx.x * 28 + r;
    if (row >= N_NODES) {
        if (FUSE_STATS) { __syncthreads(); if (tid < 72) partials[(size_t)blockIdx.x * 72 + tid] = ls[tid]; }
        return;
    }
    const unsigned long long* gb = INb + ((c < 8) ? (size_t)c : (size_t)N_NODES * 8);
    int gsh = (c < 8) ? 3 : 0;
    float ax = 0, ay = 0, az = 0, aw = 0;
    float bx = 0, by = 0, bz = 0, bw = 0;
    float cx = 0, cy = 0, cz = 0, cw = 0;
    float dx = 0, dy = 0, dz = 0, dw = 0;
    {
        int beg = rp[row], end = rp[row + 1];
        int j = beg;
        for (; j + 7 < end; j += 8) {
            unsigned v0 = csrc[j],     v1 = csrc[j + 1], v2 = csrc[j + 2], v3 = csrc[j + 3];
            unsigned v4 = csrc[j + 4], v5 = csrc[j + 5], v6 = csrc[j + 6], v7 = csrc[j + 7];
            unsigned long long q0 = gb[(size_t)esrc(v0) << gsh];
            unsigned long long q1 = gb[(size_t)esrc(v1) << gsh];
            unsigned long long q2 = gb[(size_t)esrc(v2) << gsh];
            unsigned long long q3 = gb[(size_t)esrc(v3) << gsh];
            unsigned long long q4 = gb[(size_t)esrc(v4) << gsh];
            unsigned long long q5 = gb[(size_t)esrc(v5) << gsh];
            unsigned long long q6 = gb[(size_t)esrc(v6) << gsh];
            unsigned long long q7 = gb[(size_t)esrc(v7) << gsh];
            unsigned l0 = (unsigned)q0, h0 = (unsigned)(q0 >> 32);
            unsigned l1 = (unsigned)q1, h1 = (unsigned)(q1 >> 32);
            unsigned l2 = (unsigned)q2, h2 = (unsigned)(q2 >> 32);
            unsigned l3 = (unsigned)q3, h3 = (unsigned)(q3 >> 32);
            unsigned l4 = (unsigned)q4, h4 = (unsigned)(q4 >> 32);
            unsigned l5 = (unsigned)q5, h5 = (unsigned)(q5 >> 32);
            unsigned l6 = (unsigned)q6, h6 = (unsigned)(q6 >> 32);
            unsigned l7 = (unsigned)q7, h7 = (unsigned)(q7 >> 32);
            if (WEIGHTED) {
                float w0 = ew(v0), w1 = ew(v1), w2 = ew(v2), w3 = ew(v3);
                float w4 = ew(v4), w5 = ew(v5), w6 = ew(v6), w7 = ew(v7);
                ax = fmaf(w0, bflo(l0), ax); ay = fmaf(w0, bfhi(l0), ay);
                az = fmaf(w0, bflo(h0), az); aw = fmaf(w0, bfhi(h0), aw);
                bx = fmaf(w1, bflo(l1), bx); by = fmaf(w1, bfhi(l1), by);
                bz = fmaf(w1, bflo(h1), bz); bw = fmaf(w1, bfhi(h1), bw);
                cx = fmaf(w2, bflo(l2), cx); cy = fmaf(w2, bfhi(l2), cy);
                cz = fmaf(w2, bflo(h2), cz); cw = fmaf(w2, bfhi(h2), cw);
                dx = fmaf(w3, bflo(l3), dx); dy = fmaf(w3, bfhi(l3), dy);
                dz = fmaf(w3, bflo(h3), dz); dw = fmaf(w3, bfhi(h3), dw);
                ax = fmaf(w4, bflo(l4), ax); ay = fmaf(w4, bfhi(l4), ay);
                az = fmaf(w4, bflo(h4), az); aw = fmaf(w4, bfhi(h4), aw);
                bx = fmaf(w5, bflo(l5), bx); by = fmaf(w5, bfhi(l5), by);
                bz = fmaf(w5, bflo(h5), bz); bw = fmaf(w5, bfhi(h5), bw);
                cx = fmaf(w6, bflo(l6), cx); cy = fmaf(w6, bfhi(l6), cy);
                cz = fmaf(w6, bflo(h6), cz); cw = fmaf(w6, bfhi(h6), cw);
                dx = fmaf(w7, bflo(l7), dx); dy = fmaf(w7, bfhi(l7), dy);
                dz = fmaf(w7, bflo(h7), dz); dw = fmaf(w7, bfhi(h7), dw);
            } else {
                ax += bflo(l0) + bflo(l4); ay += bfhi(l0) + bfhi(l4);
                az += bflo(h0) + bflo(h4); aw += bfhi(h0) + bfhi(h4);
                bx += bflo(l1) + bflo(l5); by += bfhi(l1) + bfhi(l5);
                bz += bflo(h1) + bflo(h5); bw += bfhi(h1) + bfhi(h5);
                cx += bflo(l2) + bflo(l6); cy += bfhi(l2) + bfhi(l6);
                cz += bflo(h2) + bflo(h6); cw += bfhi(h2) + bfhi(h6);
                dx += bflo(l3) + bflo(l7); dy += bfhi(l3) + bfhi(l7);
                dz += bflo(h3) + bflo(h7); dw += bfhi(h3) + bfhi(h7);
            }
        }
        for (; j < end; ++j) {
            unsigned v = csrc[j];
            unsigned long long q = gb[(size_t)esrc(v) << gsh];
            unsigned l = (unsigned)q, h = (unsigned)(q >> 32);
            if (WEIGHTED) {
                float w = ew(v);
                ax = fmaf(w, bflo(l), ax); ay = fmaf(w, bfhi(l), ay);
                az = fmaf(w, bflo(h), az); aw = fmaf(w, bfhi(h), aw);
            } else {
                ax += bflo(l); ay += bfhi(l);
                az += bflo(h); aw += bfhi(h);
            }
        }
        ax += bx + cx + dx; ay += by + cy + dy;
        az += bz + cz + dz; aw += bw + cw + dw;
    }
    const float S = (float)SCALE;
    unsigned long long qy = Yk[sidx(c, row)];
    unsigned ly = (unsigned)qy, hy = (unsigned)(qy >> 32);
    float ox = fmaf(S, ax, bflo(ly)), oy = fmaf(S, ay, bfhi(ly));
    float oz = fmaf(S, az, bflo(hy)), ow = fmaf(S, aw, bfhi(hy));
    if (HAS_B2) {
        unsigned long long qb = B2b[sidx(c, row)];
        unsigned lb = (unsigned)qb, hb = (unsigned)(qb >> 32);
        ox -= bflo(lb); oy -= bfhi(lb);
        oz -= bflo(hb); ow -= bfhi(hb);
    }
    if (BIAS_RELU) {
        int cb = c * 4;
        ox = fmaxf(ox + bias[cb + 0], 0.f); oy = fmaxf(oy + bias[cb + 1], 0.f);
        oz = fmaxf(oz + bias[cb + 2], 0.f); ow = fmaxf(ow + bias[cb + 3], 0.f);
    }
    unsigned long long pv = (unsigned long long)bf16pack(ox, oy)
                          | ((unsigned long long)bf16pack(oz, ow) << 32);
    OUT[sidx(c, row)] = pv;
    if (FUSE_STATS) {
        atomicAdd(&ls[c * 4 + 0], ox); atomicAdd(&ls[36 + c * 4 + 0], ox * ox);
        atomicAdd(&ls[c * 4 + 1], oy); atomicAdd(&ls[36 + c * 4 + 1], oy * oy);
        atomicAdd(&ls[c * 4 + 2], oz); atomicAdd(&ls[36 + c * 4 + 2], oz * oz);
        atomicAdd(&ls[c * 4 + 3], ow); atomicAdd(&ls[36 + c * 4 + 3], ow * ow);
        __syncthreads();
        if (tid < 72) partials[(size_t)blockIdx.x * 72 + tid] = ls[tid];
    }
}

// ---------------- finalize: reduce partials -> BN scale/shift ----------------

__global__ __launch_bounds__(256) void finalize_kernel(
    const float* __restrict__ partials, int nb, const float* __restrict__ g,
    const float* __restrict__ be, float* __restrict__ ss) {
    __shared__ float rs[256], rq[256];
    int c = blockIdx.x;
    int t = threadIdx.x;
    float s = 0.f, q = 0.f;
    for (int i = t; i < nb; i += 256) {
        s += partials[(size_t)i * 72 + c];
        q += partials[(size_t)i * 72 + c + 36];
    }
    rs[t] = s; rq[t] = q;
    __syncthreads();
    for (int off = 128; off > 0; off >>= 1) {
        if (t < off) { rs[t] += rs[t + off]; rq[t] += rq[t + off]; }
        __syncthreads();
    }
    if (t == 0) {
        float m = rs[0] / (float)N_NODES;
        float v = rq[0] / (float)N_NODES - m * m;
        float sc = g[c] * rsqrtf(v + 1e-5f);
        ss[c] = sc;
        ss[36 + c] = be[c] - m * sc;
    }
}

// ---------------- final concat GEMM, split-layout bf16 inputs (32 rows/block) ----

__global__ __launch_bounds__(256) void fused3_kernel(
    const unsigned long long* __restrict__ X1b, const float* __restrict__ ssA,
    const unsigned long long* __restrict__ X2b, const float* __restrict__ ssB,
    const unsigned long long* __restrict__ X3b, const float* __restrict__ ssC,
    const float* __restrict__ W, const float* __restrict__ b,
    float* __restrict__ out) {
    __shared__ float Wl[108 * 32];
    __shared__ float Al[32][109];
    int tid = threadIdx.x;
    for (int i = tid; i < 108 * 32; i += 256) Wl[i] = W[i];
    int r0 = blockIdx.x * 32;
    for (int i = tid; i < 32 * 108; i += 256) {
        int r = i / 108, f = i % 108;
        int row = r0 + r;
        float v = 0.f;
        if (row < N_NODES) {
            int t = f / 36, ff = f % 36;
            const unsigned short* b16 =
                (const unsigned short*)(t == 0 ? X1b : (t == 1 ? X2b : X3b));
            unsigned short u16 = (ff < 32)
                ? b16[(size_t)row * 32 + ff]
                : b16[(size_t)N_NODES * 32 + (size_t)row * 4 + (ff - 32)];
            float xv = __uint_as_float((unsigned)u16 << 16);
            if (t == 0)      v = fmaxf(fmaf(ssA[ff], xv, ssA[36 + ff]), 0.f);
            else if (t == 1) v = fmaxf(fmaf(ssB[ff], xv, ssB[36 + ff]), 0.f);
            else             v = fmaf(ssC[ff], xv, ssC[36 + ff]);
        }
        Al[r][f] = v;
    }
    __syncthreads();
    int r = tid >> 3, q = tid & 7;
    int row = r0 + r;
    if (row >= N_NODES) return;
    float acc[4];
#pragma unroll
    for (int j = 0; j < 4; ++j) acc[j] = b[q * 4 + j];
    for (int f = 0; f < 108; ++f) {
        float a = Al[r][f];
#pragma unroll
        for (int j = 0; j < 4; ++j)
            acc[j] = fmaf(a, Wl[f * 32 + q * 4 + j], acc[j]);
    }
#pragma unroll
    for (int j = 0; j < 4; ++j) out[(size_t)row * 32 + q * 4 + j] = acc[j];
}

// ---------------- launch ----------------

extern "C" void kernel_launch(void* const* d_in, const int* in_sizes, int n_in,
                              void* d_out, int out_size, void* d_ws, size_t ws_size,
                              hipStream_t stream) {
    const float* x      = (const float*)d_in[0];
    const int*   ei     = (const int*)d_in[1];
    const float* W1_1   = (const float*)d_in[2];
    // b1_1 / b1_2 cancel exactly under training-mode BN -> dropped.
    const float* g1_1   = (const float*)d_in[4];
    const float* be1_1  = (const float*)d_in[5];
    const float* W1_2   = (const float*)d_in[6];
    const float* g1_2   = (const float*)d_in[8];
    const float* be1_2  = (const float*)d_in[9];
    const float* gin_w1 = (const float*)d_in[10];
    const float* gin_b1 = (const float*)d_in[11];
    const float* gin_w2 = (const float*)d_in[12];
    const float* gin_b2 = (const float*)d_in[13];
    const float* g2     = (const float*)d_in[14];
    const float* be2    = (const float*)d_in[15];
    const float* W4     = (const float*)d_in[16];
    const float* b4     = (const float*)d_in[17];
    float* out = (float*)d_out;

    char* ws = (char*)d_ws;
    size_t off = 0;
    auto alloc = [&](size_t bytes) -> char* {
        char* p = ws + off;
        off = (off + bytes + 255) & ~(size_t)255;
        return p;
    };
    int*   rp    = (int*)alloc((size_t)(N_NODES + 1) * 4);
    unsigned* csrc = (unsigned*)alloc((size_t)N_EDGES * 4);
    float* ssA   = (float*)alloc(72 * 4);
    float* ssB   = (float*)alloc(72 * 4);
    float* ssC   = (float*)alloc(72 * 4);
    float* partials = (float*)alloc((size_t)6250 * 72 * 4);
    uint2* xbf = (uint2*)alloc((size_t)N_NODES * 128);     // bf16 [N,64] 128B rows
    // Y region: 9 split-buffers (64.8MB); preproc temps carved inside (dead after)
    char*  U = alloc(9 * YST * 8);
    unsigned long long* Yall = (unsigned long long*)U;
    constexpr size_t NBBF = (size_t)N_NODES * 72;
    unsigned long long* R0  = (unsigned long long*)alloc(NBBF);
    unsigned long long* R1  = (unsigned long long*)alloc(NBBF);
    unsigned long long* R2  = (unsigned long long*)alloc(NBBF);
    unsigned long long* X1b = (unsigned long long*)alloc(NBBF);
    unsigned long long* X2b = (unsigned long long*)alloc(NBBF);
    unsigned long long* X3b = (unsigned long long*)alloc(NBBF);
    if (off > ws_size) return;

    // preproc temps inside U
    int*   cntD = (int*)U;
    int*   cntS = cntD + LCNT;
    int*   bsum = cntS + LCNT;
    float* dis  = (float*)(bsum + 1024);
    int2*  edgepart = (int2*)(dis + N_NODES);
    int*   srcpart  = (int*)(edgepart + N_EDGES);

    part_count_kernel<<<NBLK, 256, 0, stream>>>(ei, cntD, cntS);
    scanA_kernel<<<SCAN_BLKS, 256, 0, stream>>>(cntD, cntD, bsum, LCNT);
    scanB_kernel<<<1, 1024, 0, stream>>>(bsum, SCAN_BLKS);
    scanC_kernel<<<SCAN_BLKS, 256, 0, stream>>>(cntD, bsum, LCNT);
    scanA_kernel<<<SCAN_BLKS, 256, 0, stream>>>(cntS, cntS, bsum, LCNT);
    scanB_kernel<<<1, 1024, 0, stream>>>(bsum, SCAN_BLKS);
    scanC_kernel<<<SCAN_BLKS, 256, 0, stream>>>(cntS, bsum, LCNT);
    part_scatter_kernel<<<NBLK, 256, 0, stream>>>(ei, cntD, cntS, edgepart, srcpart);
    deg_kernel<<<NBK, 256, 0, stream>>>(srcpart, cntS, dis);
    csr_kernel<<<NBK, 256, 0, stream>>>(edgepart, cntD, dis, rp, csrc);
    pack_x_kernel<<<(N_NODES * 16 + 255) / 256, 256, 0, stream>>>(x, xbf);

    const int BLKS = (N_NODES + 27) / 28;      // 3572 (gsteps)
    const int PBLKS = (N_NODES + 111) / 112;   // 893  (batchproj row-blocks)
    const int F3_BLKS = (N_NODES + 31) / 32;   // 3125
    const unsigned long long* xb64 = (const unsigned long long*)xbf;
    auto Y = [&](int k) { return Yall + (size_t)k * YST; };

    // ---- conv1_1: batched proj (9 kk over 3 chunks), then 7 light steps ----
    batchproj_kernel<64, 8, 3, false, true, false, false><<<PBLKS * 3, 252, 0, stream>>>(
        xb64, W1_1, gin_w1, nullptr, nullptr, Yall, nullptr, PBLKS);
    gstep_kernel<2, true, false, false, false><<<BLKS, 252, 0, stream>>>(
        rp, csrc, Y(7), Y(6), nullptr, nullptr, R0, nullptr);
    gstep_kernel<2, true, true, false, false><<<BLKS, 252, 0, stream>>>(
        rp, csrc, R0, Y(5), Y(7), nullptr, R1, nullptr);
    gstep_kernel<2, true, true, false, false><<<BLKS, 252, 0, stream>>>(
        rp, csrc, R1, Y(4), R0, nullptr, R2, nullptr);
    gstep_kernel<2, true, true, false, false><<<BLKS, 252, 0, stream>>>(
        rp, csrc, R2, Y(3), R1, nullptr, R0, nullptr);
    gstep_kernel<2, true, true, false, false><<<BLKS, 252, 0, stream>>>(
        rp, csrc, R0, Y(2), R2, nullptr, R1, nullptr);
    gstep_kernel<2, true, true, false, false><<<BLKS, 252, 0, stream>>>(
        rp, csrc, R1, Y(1), R0, nullptr, R2, nullptr);
    gstep_kernel<1, true, true, false, true><<<BLKS, 252, 0, stream>>>(
        rp, csrc, R2, Y(0), R1, nullptr, X1b, partials);
    finalize_kernel<<<36, 256, 0, stream>>>(partials, BLKS, g1_1, be1_1, ssA);

    // ---- GIN: m1 = relu(Y8_self + sum Y8_src + b1) -> R0; X3 = relu(m1@w2+b2)+stats ----
    gstep_kernel<1, false, false, true, false><<<BLKS, 252, 0, stream>>>(
        rp, csrc, Y(8), Y(8), nullptr, gin_b1, R0, nullptr);
    batchproj_kernel<36, 1, 1, false, false, true, true><<<PBLKS, 252, 0, stream>>>(
        R0, gin_w2, nullptr, nullptr, gin_b2, X3b, partials, PBLKS);
    finalize_kernel<<<36, 256, 0, stream>>>(partials, PBLKS, g2, be2, ssC);

    // ---- conv1_2: batched proj of bn(X1b) (8 kk over 3 chunks), then 7 steps ----
    batchproj_kernel<36, 8, 3, true, false, false, false><<<PBLKS * 3, 252, 0, stream>>>(
        X1b, W1_2, nullptr, ssA, nullptr, Yall, nullptr, PBLKS);
    gstep_kernel<2, true, false, false, false><<<BLKS, 252, 0, stream>>>(
        rp, csrc, Y(7), Y(6), nullptr, nullptr, R0, nullptr);
    gstep_kernel<2, true, true, false, false><<<BLKS, 252, 0, stream>>>(
        rp, csrc, R0, Y(5), Y(7), nullptr, R1, nullptr);
    gstep_kernel<2, true, true, false, false><<<BLKS, 252, 0, stream>>>(
        rp, csrc, R1, Y(4), R0, nullptr, R2, nullptr);
    gstep_kernel<2, true, true, false, false><<<BLKS, 252, 0, stream>>>(
        rp, csrc, R2, Y(3), R1, nullptr, R0, nullptr);
    gstep_kernel<2, true, true, false, false><<<BLKS, 252, 0, stream>>>(
        rp, csrc, R0, Y(2), R2, nullptr, R1, nullptr);
    gstep_kernel<2, true, true, false, false><<<BLKS, 252, 0, stream>>>(
        rp, csrc, R1, Y(1), R0, nullptr, R2, nullptr);
    gstep_kernel<1, true, true, false, true><<<BLKS, 252, 0, stream>>>(
        rp, csrc, R2, Y(0), R1, nullptr, X2b, partials);
    finalize_kernel<<<36, 256, 0, stream>>>(partials, BLKS, g1_2, be1_2, ssB);

    // ---- final concat GEMM ----
    fused3_kernel<<<F3_BLKS, 256, 0, stream>>>(X1b, ssA, X2b, ssB, X3b, ssC, W4, b4, out);
}